// Round 4
// baseline (240.908 us; speedup 1.0000x reference)
//
#include <hip/hip_runtime.h>
#include <math.h>

#define K_POLY   20000
#define PMAX     30
#define NUM_PTS  5
#define C_MID    112
#define C_OUT    224
#define PE_DIM   32
#define GEO_DIM  256

#define POLYS_A  8                       // polys per prep block
#define WP_ELEMS (21*7*64*8)             // 75264 bf16 = 150528 B
#define Y1_ROW   (7*C_MID)               // 784 bf16 per poly (halo layout)
#define M_ROWS   (K_POLY*NUM_PTS)        // 100000
#define MB       64                      // rows per gemm block (2 M-tiles)
#define GRID_B   ((M_ROWS + MB - 1)/MB)  // 1563

typedef __attribute__((ext_vector_type(8)))  short short8;
typedef __attribute__((ext_vector_type(16))) float f32x16;

__device__ inline unsigned short f2bf(float f) {
    union { float f; unsigned u; } v; v.f = f;
    return (unsigned short)((v.u + 0x7fffu + ((v.u >> 16) & 1u)) >> 16);
}

// ============ Kernel A: pack w2 + resample + PE + conv1 -> y1 (global bf16) ============
__global__ __launch_bounds__(256) void prep_kernel(
    const float* __restrict__ geoms, const int* __restrict__ lengths,
    const float* __restrict__ w1, const float* __restrict__ b1,
    const float* __restrict__ w2,
    const int* __restrict__ roi_w, const int* __restrict__ roi_h,
    unsigned short* __restrict__ Wp, unsigned short* __restrict__ y1g,
    float* __restrict__ out)
{
    __shared__ float s_geo[POLYS_A][PMAX][2];
    __shared__ float s_cum[POLYS_A][PMAX];
    __shared__ float s_seg[POLYS_A][PMAX - 1];
    __shared__ float s_pts[POLYS_A][NUM_PTS][2];
    __shared__ float s_w1[C_MID * 6];
    __shared__ float s_b1[C_MID];
    __shared__ int   s_len[POLYS_A];

    const int t  = threadIdx.x;
    const int k0 = blockIdx.x * POLYS_A;

    // ---- pack w2 into B-fragment order: Wp[((ks*7+nt)*64 + lane)*8 + j] ----
    {
        int gtid = blockIdx.x * 256 + t;
        if (gtid < WP_ELEMS) {
            int j    = gtid & 7;
            int lane = (gtid >> 3) & 63;
            int grp  = gtid >> 9;          // ks*7 + nt
            int nt   = grp % 7;
            int ks   = grp / 7;
            int kh   = lane >> 5, n = lane & 31;
            int k    = ks * 16 + kh * 8 + j;   // 0..335, k = dk*112 + c
            int dk   = k / C_MID;
            int c    = k - dk * C_MID;
            int o    = nt * 32 + n;
            Wp[gtid] = f2bf(w2[(o * C_MID + c) * 3 + dk]);
        }
    }

    // ---- stage ----
    {
        const float* src = geoms + (size_t)k0 * (PMAX * 2);
        float* dst = &s_geo[0][0][0];
        for (int i = t; i < POLYS_A * PMAX * 2; i += 256) dst[i] = src[i];
        if (t < POLYS_A) s_len[t] = lengths[k0 + t];
        for (int i = t; i < C_MID * 6; i += 256) s_w1[i] = w1[i];
        if (t < C_MID) s_b1[t] = b1[t];
    }
    __syncthreads();

    // ---- per-poly cum/seg (bitwise cumsum order) ----
    if (t < POLYS_A) {
        int L = s_len[t];
        float cum = 0.f;
        s_cum[t][0] = 0.f;
        for (int i = 0; i < PMAX - 1; ++i) {
            float seg = 0.f;
            if (i < L - 1) {
                float dx = s_geo[t][i + 1][0] - s_geo[t][i][0];
                float dy = s_geo[t][i + 1][1] - s_geo[t][i][1];
                float sq = dx * dx + dy * dy;
                seg = (sq > 0.f) ? sqrtf(sq) : 0.f;
            }
            s_seg[t][i] = seg;
            cum += seg;
            s_cum[t][i + 1] = cum;
        }
    }
    __syncthreads();

    // ---- resample ----
    const float roiw  = (float)roi_w[0], roih = (float)roi_h[0];
    const float halfx = roiw * 0.5f, halfy = roih * 0.5f;
    if (t < POLYS_A * NUM_PTS) {
        int poly = t / NUM_PTS, j = t % NUM_PTS;
        int L = s_len[poly];
        float total = s_cum[poly][PMAX - 1];
        float px, py;
        if (total < 1e-6f) {
            px = s_geo[poly][0][0];
            py = s_geo[poly][0][1];
        } else {
            float target = total * (0.25f * (float)j);
            int idx = PMAX;
            for (int i = 0; i < PMAX; ++i) {
                if (s_cum[poly][i] >= target) { idx = i; break; }
            }
            idx = max(1, min(idx, L - 1));
            float tt = (target - s_cum[poly][idx - 1]) / (s_seg[poly][idx - 1] + 1e-8f);
            float x0 = s_geo[poly][idx - 1][0], y0 = s_geo[poly][idx - 1][1];
            px = x0 + tt * (s_geo[poly][idx][0] - x0);
            py = y0 + tt * (s_geo[poly][idx][1] - y0);
        }
        float cx = (px + halfx) / roiw;
        float cy = (py + halfy) / roih;
        s_pts[poly][j][0] = cx;
        s_pts[poly][j][1] = cy;
        float* co = out + (size_t)K_POLY * NUM_PTS * GEO_DIM + ((size_t)(k0 + poly) * NUM_PTS + j) * 2;
        co[0] = cx;
        co[1] = cy;
    }
    __syncthreads();

    // ---- PE: channels 0..31 ----
    for (int i = t; i < POLYS_A * NUM_PTS * PE_DIM; i += 256) {
        int poly = i / (NUM_PTS * PE_DIM);
        int r = i % (NUM_PTS * PE_DIM);
        int p = r / PE_DIM;
        int f = r % PE_DIM;
        int d = f >> 4;
        int inner = f & 15;
        int fr = inner & 7;
        int isc = inner >> 3;
        float x = s_pts[poly][p][d];
        float arg = x * ((float)(1 << fr) * 3.14159265358979323846f);
        float v = isc ? __cosf(arg) : __sinf(arg);
        out[((size_t)(k0 + poly) * NUM_PTS + p) * GEO_DIM + f] = v;
    }

    // ---- conv1 + ReLU -> y1 global bf16, halo layout [poly][7][112], paired stores ----
    for (int i = t; i < POLYS_A * 7 * (C_MID / 2); i += 256) {
        int poly = i / (7 * (C_MID / 2));
        int r = i % (7 * (C_MID / 2));
        int slot = r / (C_MID / 2);
        int cp = r % (C_MID / 2);
        unsigned int pairv = 0;
        if (slot >= 1 && slot <= 5) {
            int p = slot - 1;
            #pragma unroll
            for (int h = 0; h < 2; ++h) {
                int c = cp * 2 + h;
                float acc = s_b1[c];
                const float* w = &s_w1[c * 6];
                #pragma unroll
                for (int ch = 0; ch < 2; ++ch) {
                    #pragma unroll
                    for (int dk = 0; dk < 3; ++dk) {
                        int pp = p + dk - 1;
                        float xv = (pp >= 0 && pp < NUM_PTS) ? s_pts[poly][pp][ch] : 0.f;
                        acc += xv * w[ch * 3 + dk];
                    }
                }
                pairv |= ((unsigned int)f2bf(fmaxf(acc, 0.f))) << (16 * h);
            }
        }
        ((unsigned int*)y1g)[((size_t)(k0 + poly) * 7 + slot) * (C_MID / 2) + cp] = pairv;
    }
}

// ============ Kernel B: GEMM (conv2) + ReLU + cross-wave LayerNorm ============
// Block = 4 waves, 64 rows (2 M-tiles of 32). Wave w owns n-tiles {w, w+4}.
__global__ __launch_bounds__(256, 3) void gemm_kernel(
    const unsigned short* __restrict__ y1g, const unsigned short* __restrict__ Wp,
    const float* __restrict__ b2, const float* __restrict__ gamma,
    const float* __restrict__ beta, float* __restrict__ out)
{
    __shared__ float s_part[2][32][4][2];   // [mt][row][wave][s,q]
    __shared__ float s_stats[2][32][2];     // [mt][row][mu,rstd]

    const int wave = threadIdx.x >> 6;
    const int lane = threadIdx.x & 63;
    const int n    = lane & 31;
    const int kh   = lane >> 5;
    const int base = blockIdx.x * MB;

    const int ntA = wave;
    const int ntB = wave + 4;
    const bool hasB = (ntB < 7);

    // A pointers for the two M-tiles (clamped for the tail block)
    int r0c = min(base + n,      M_ROWS - 1);
    int r1c = min(base + 32 + n, M_ROWS - 1);
    int poly0 = r0c / NUM_PTS, p0 = r0c - poly0 * NUM_PTS;
    int poly1 = r1c / NUM_PTS, p1 = r1c - poly1 * NUM_PTS;
    const unsigned short* ap0 = y1g + ((size_t)poly0 * 7 + p0) * C_MID + kh * 8;
    const unsigned short* ap1 = y1g + ((size_t)poly1 * 7 + p1) * C_MID + kh * 8;
    const unsigned short* wlA = Wp + (ntA * 64 + lane) * 8;
    const unsigned short* wlB = Wp + (ntB * 64 + lane) * 8;

    f32x16 accA0, accA1, accB0, accB1;
    #pragma unroll
    for (int i = 0; i < 16; ++i) { accA0[i] = 0.f; accA1[i] = 0.f; accB0[i] = 0.f; accB1[i] = 0.f; }

    #pragma unroll 3
    for (int ks = 0; ks < 21; ++ks) {
        short8 a0 = *(const short8*)(ap0 + ks * 16);
        short8 a1 = *(const short8*)(ap1 + ks * 16);
        short8 bA = *(const short8*)(wlA + ks * (7 * 512));
        accA0 = __builtin_amdgcn_mfma_f32_32x32x16_bf16(a0, bA, accA0, 0, 0, 0);
        accA1 = __builtin_amdgcn_mfma_f32_32x32x16_bf16(a1, bA, accA1, 0, 0, 0);
        if (hasB) {
            short8 bB = *(const short8*)(wlB + ks * (7 * 512));
            accB0 = __builtin_amdgcn_mfma_f32_32x32x16_bf16(a0, bB, accB0, 0, 0, 0);
            accB1 = __builtin_amdgcn_mfma_f32_32x32x16_bf16(a1, bB, accB1, 0, 0, 0);
        }
    }

    float biasA = b2[ntA * 32 + n], gA = gamma[ntA * 32 + n], beA = beta[ntA * 32 + n];
    float biasB = 0.f, gB = 0.f, beB = 0.f;
    if (hasB) { biasB = b2[ntB * 32 + n]; gB = gamma[ntB * 32 + n]; beB = beta[ntB * 32 + n]; }

    // bias + ReLU in place; per-row partial sums over this wave's cols
    #pragma unroll
    for (int mt = 0; mt < 2; ++mt) {
        f32x16& aA = mt ? accA1 : accA0;
        f32x16& aB = mt ? accB1 : accB0;
        #pragma unroll
        for (int i = 0; i < 16; ++i) {
            float vA = fmaxf(aA[i] + biasA, 0.f);
            float vB = hasB ? fmaxf(aB[i] + biasB, 0.f) : 0.f;
            aA[i] = vA; aB[i] = vB;
            float s = vA + vB;
            float q = vA * vA + vB * vB;
            #pragma unroll
            for (int m = 16; m >= 1; m >>= 1) {
                s += __shfl_xor(s, m, 64);
                q += __shfl_xor(q, m, 64);
            }
            if (n == 0) {
                int row = (i & 3) + 8 * (i >> 2) + 4 * kh;
                s_part[mt][row][wave][0] = s;
                s_part[mt][row][wave][1] = q;
            }
        }
    }
    __syncthreads();
    if (threadIdx.x < 64) {
        int mt = threadIdx.x >> 5, row = threadIdx.x & 31;
        float s = 0.f, q = 0.f;
        #pragma unroll
        for (int w = 0; w < 4; ++w) {
            s += s_part[mt][row][w][0];
            q += s_part[mt][row][w][1];
        }
        float mu  = s * (1.f / C_OUT);
        float var = fmaxf(q * (1.f / C_OUT) - mu * mu, 0.f);
        s_stats[mt][row][0] = mu;
        s_stats[mt][row][1] = rsqrtf(var + 1e-5f);
    }
    __syncthreads();

    #pragma unroll
    for (int mt = 0; mt < 2; ++mt) {
        f32x16& aA = mt ? accA1 : accA0;
        f32x16& aB = mt ? accB1 : accB0;
        #pragma unroll
        for (int i = 0; i < 16; ++i) {
            int row = (i & 3) + 8 * (i >> 2) + 4 * kh;
            int rg = base + mt * 32 + row;
            if (rg < M_ROWS) {
                float mu = s_stats[mt][row][0], rs = s_stats[mt][row][1];
                size_t ob = (size_t)rg * GEO_DIM + PE_DIM + n;
                __builtin_nontemporal_store((aA[i] - mu) * rs * gA + beA, &out[ob + ntA * 32]);
                if (hasB)
                    __builtin_nontemporal_store((aB[i] - mu) * rs * gB + beB, &out[ob + ntB * 32]);
            }
        }
    }
}

extern "C" void kernel_launch(void* const* d_in, const int* in_sizes, int n_in,
                              void* d_out, int out_size, void* d_ws, size_t ws_size,
                              hipStream_t stream) {
    const float* geoms   = (const float*)d_in[0];
    const int*   lengths = (const int*)d_in[1];
    const float* w1      = (const float*)d_in[2];
    const float* b1      = (const float*)d_in[3];
    const float* w2      = (const float*)d_in[4];
    const float* b2      = (const float*)d_in[5];
    const float* gamma   = (const float*)d_in[6];
    const float* beta    = (const float*)d_in[7];
    const int*   roi_w   = (const int*)d_in[8];
    const int*   roi_h   = (const int*)d_in[9];
    float* out = (float*)d_out;

    unsigned short* Wp  = (unsigned short*)d_ws;            // 150528 B
    unsigned short* y1g = (unsigned short*)d_ws + WP_ELEMS; // 20000*784*2 B

    hipLaunchKernelGGL(prep_kernel, dim3(K_POLY / POLYS_A), dim3(256), 0, stream,
                       geoms, lengths, w1, b1, w2, roi_w, roi_h, Wp, y1g, out);
    hipLaunchKernelGGL(gemm_kernel, dim3(GRID_B), dim3(256), 0, stream,
                       y1g, Wp, b2, gamma, beta, out);
}